// Round 1
// baseline (672.892 us; speedup 1.0000x reference)
//
#include <hip/hip_runtime.h>
#include <stdint.h>

typedef __attribute__((ext_vector_type(4))) float f32x4;
typedef __attribute__((ext_vector_type(4))) float float4v;
typedef __attribute__((ext_vector_type(8))) short short8;
typedef __attribute__((ext_vector_type(4))) unsigned short ushort4v;

// ---------- helpers ----------

__device__ __forceinline__ unsigned short f2bf(float f) {
  union { float f; unsigned u; } cv; cv.f = f;
  return (unsigned short)((cv.u + 0x7fffu + ((cv.u >> 16) & 1u)) >> 16);
}

__device__ __forceinline__ void gload_lds16(const unsigned short* g, unsigned short* lds) {
  __builtin_amdgcn_global_load_lds(
      (const __attribute__((address_space(1))) void*)g,
      (__attribute__((address_space(3))) void*)lds, 16, 0, 0);
}

__device__ __forceinline__ void mfma_bf16(f32x4& acc, short8 a, short8 b) {
  asm("v_mfma_f32_16x16x32_bf16 %0, %1, %2, %0" : "+v"(acc) : "v"(a), "v"(b));
}

// ---------- kernel 1: x(fp32 [N][D]) -> xt(bf16 [D][N]) and xb(bf16 [N][D]) ----------

__global__ __launch_bounds__(256) void transpose_convert(
    const float* __restrict__ x, unsigned short* __restrict__ xt,
    unsigned short* __restrict__ xb) {
  const int D = 4096, N = 8192;
  __shared__ float tile[32][33];
  int dx = blockIdx.x * 32 + threadIdx.x;   // D index
  int ny = blockIdx.y * 32 + threadIdx.y;   // N index
#pragma unroll
  for (int j = 0; j < 32; j += 8) {
    float v = x[(size_t)(ny + j) * D + dx];
    tile[threadIdx.y + j][threadIdx.x] = v;
    xb[(size_t)(ny + j) * D + dx] = f2bf(v);
  }
  __syncthreads();
  int dy = blockIdx.x * 32 + threadIdx.y;   // D index (xt row)
  int nx = blockIdx.y * 32 + threadIdx.x;   // N index (xt col)
#pragma unroll
  for (int j = 0; j < 32; j += 8)
    xt[(size_t)(dy + j) * N + nx] = f2bf(tile[threadIdx.x][threadIdx.y + j]);
}

// ---------- kernel 2/4: C[M][N] (fp32) = A[M][K] * B[N][K]^T  (bf16 in, m97 structure) ----------

__global__ __launch_bounds__(256) void gemm_bt(
    const unsigned short* __restrict__ A, const unsigned short* __restrict__ B,
    float* __restrict__ C, int M, int N, int K) {
  __shared__ __align__(16) unsigned short As[128 * 32];
  __shared__ __align__(16) unsigned short Bs[128 * 32];
  const int mtiles = M >> 7;
  const int tm = blockIdx.x % mtiles;
  const int tn = blockIdx.x / mtiles;
  const size_t m0 = (size_t)tm * 128, n0 = (size_t)tn * 128;
  const int t = threadIdx.x;
  const int w = t >> 6, lane = t & 63;
  const int wr = w >> 1, wc = w & 1;
  const int mlane = lane & 15, kgrp = lane >> 4;

  f32x4 acc[4][4] = {};

  // staging: each thread owns chunk t and chunk t+256 of each 8KB tile
  const int row0 = t >> 2, slot0 = t & 3;
  const unsigned short* gA0 = A + (m0 + row0) * (size_t)K + slot0 * 8;
  const unsigned short* gA1 = A + (m0 + 64 + row0) * (size_t)K + slot0 * 8;
  const unsigned short* gB0 = B + (n0 + row0) * (size_t)K + slot0 * 8;
  const unsigned short* gB1 = B + (n0 + 64 + row0) * (size_t)K + slot0 * 8;
  unsigned short* lA0 = As + w * 512;          // byte w*1024, lane adds l*16
  unsigned short* lA1 = As + 2048 + w * 512;
  unsigned short* lB0 = Bs + w * 512;
  unsigned short* lB1 = Bs + 2048 + w * 512;

  const int aoff = (wr * 64 + mlane) * 32 + kgrp * 8;  // + i*512
  const int boff = (wc * 64 + mlane) * 32 + kgrp * 8;  // + j*512

  for (int k0 = 0; k0 < K; k0 += 32) {
    __syncthreads();                 // prior iter's ds_reads done before overwrite
    gload_lds16(gA0 + k0, lA0);
    gload_lds16(gA1 + k0, lA1);
    gload_lds16(gB0 + k0, lB0);
    gload_lds16(gB1 + k0, lB1);
    __syncthreads();                 // drains vmcnt -> tile visible
    short8 af[4], bf[4];
#pragma unroll
    for (int i = 0; i < 4; ++i) {
      af[i] = *reinterpret_cast<const short8*>(&As[aoff + i * 512]);
      bf[i] = *reinterpret_cast<const short8*>(&Bs[boff + i * 512]);
    }
#pragma unroll
    for (int i = 0; i < 4; ++i)
#pragma unroll
      for (int j = 0; j < 4; ++j) mfma_bf16(acc[i][j], af[i], bf[j]);
  }

  // epilogue: D row=(lane>>4)*4+r, col=lane&15 within each 16x16 fragment
#pragma unroll
  for (int i = 0; i < 4; ++i) {
    size_t r0 = m0 + wr * 64 + i * 16 + kgrp * 4;
#pragma unroll
    for (int j = 0; j < 4; ++j) {
      size_t c0 = n0 + wc * 64 + j * 16 + mlane;
      float* cp = C + r0 * (size_t)N + c0;
#pragma unroll
      for (int r = 0; r < 4; ++r) cp[(size_t)r * N] = acc[i][j][r];
    }
  }
}

// ---------- kernel 3: column softmax via symmetry -> bt (bf16 [D][D], bt[j][i]=b[i][j]) ----------

__global__ __launch_bounds__(256) void softmax_rows(
    const float* __restrict__ a, unsigned short* __restrict__ bt) {
  const int D = 4096;
  const int row = blockIdx.x;
  const float* ar = a + (size_t)row * D;
  unsigned short* br = bt + (size_t)row * D;
  const int t = threadIdx.x;

  float4v v[4];
  float mx = -3.4e38f;
#pragma unroll
  for (int p = 0; p < 4; ++p) {
    v[p] = *reinterpret_cast<const float4v*>(&ar[p * 1024 + t * 4]);
#pragma unroll
    for (int q = 0; q < 4; ++q) mx = fmaxf(mx, v[p][q]);
  }
#pragma unroll
  for (int o = 32; o >= 1; o >>= 1) mx = fmaxf(mx, __shfl_xor(mx, o));
  __shared__ float redm[4], reds[4];
  if ((t & 63) == 0) redm[t >> 6] = mx;
  __syncthreads();
  mx = fmaxf(fmaxf(redm[0], redm[1]), fmaxf(redm[2], redm[3]));

  float e[16];
  float s = 0.f;
#pragma unroll
  for (int p = 0; p < 4; ++p)
#pragma unroll
    for (int q = 0; q < 4; ++q) {
      float ev = __expf(v[p][q] - mx);
      e[p * 4 + q] = ev;
      s += ev;
    }
#pragma unroll
  for (int o = 32; o >= 1; o >>= 1) s += __shfl_xor(s, o);
  if ((t & 63) == 0) reds[t >> 6] = s;
  __syncthreads();
  s = reds[0] + reds[1] + reds[2] + reds[3];
  float inv = 1.0f / s;

#pragma unroll
  for (int p = 0; p < 4; ++p) {
    ushort4v o4;
#pragma unroll
    for (int q = 0; q < 4; ++q) o4[q] = f2bf(e[p * 4 + q] * inv);
    *reinterpret_cast<ushort4v*>(&br[p * 1024 + t * 4]) = o4;
  }
}

// ---------- launch ----------

extern "C" void kernel_launch(void* const* d_in, const int* in_sizes, int n_in,
                              void* d_out, int out_size, void* d_ws, size_t ws_size,
                              hipStream_t stream) {
  const int N = 8192, D = 4096;
  const float* x = (const float*)d_in[0];
  float* out = (float*)d_out;
  uint8_t* ws = (uint8_t*)d_ws;

  unsigned short* xt = (unsigned short*)ws;                           // 64 MB bf16 [D][N]
  unsigned short* xb = (unsigned short*)(ws + ((size_t)64 << 20));    // 64 MB bf16 [N][D]
  unsigned short* bt = (unsigned short*)(ws + ((size_t)128 << 20));   // 32 MB bf16 [D][D]
  float* a = out;  // Gram matrix staged in d_out's first 64 MB (overwritten by GEMM2 later)

  transpose_convert<<<dim3(D / 32, N / 32), dim3(32, 8), 0, stream>>>(x, xt, xb);
  gemm_bt<<<dim3((D / 128) * (D / 128)), dim3(256), 0, stream>>>(xt, xt, a, D, D, N);
  softmax_rows<<<dim3(D), dim3(256), 0, stream>>>(a, bt);
  gemm_bt<<<dim3((N / 128) * (D / 128)), dim3(256), 0, stream>>>(xb, bt, out, N, D, D);
}